// Round 1
// baseline (757.265 us; speedup 1.0000x reference)
//
#include <hip/hip_runtime.h>
#include <cstdint>
#include <cstddef>

// Problem constants (B=2, S=4096 -> T=8192 tokens)
#define T_TOK 8192
#define DIM   1024   // D
#define NE    8      // experts
#define FF    2048   // F
#define TOPK  2

typedef __bf16 bf16x8 __attribute__((ext_vector_type(8)));
typedef float  floatx4 __attribute__((ext_vector_type(4)));

__device__ __forceinline__ unsigned short f2bf(float f) {
  unsigned int u = __float_as_uint(f);
  unsigned int r = 0x7FFFu + ((u >> 16) & 1u);   // round-to-nearest-even
  return (unsigned short)((u + r) >> 16);
}

__device__ __forceinline__ void gl_lds16(const void* g, void* l) {
  __builtin_amdgcn_global_load_lds(
      (__attribute__((address_space(1))) void*)g,
      (__attribute__((address_space(3))) void*)l,
      16, 0, 0);
}

// ---------------------------------------------------------------------------
// Transpose + f32->bf16 convert:  in[e][r][c] (f32) -> out[e][c][r] (bf16)
// ---------------------------------------------------------------------------
__global__ __launch_bounds__(256) void transpose_bf16_kernel(
    const float* __restrict__ in, unsigned short* __restrict__ out,
    int R, int C)
{
  __shared__ float tile[32][33];
  int e  = blockIdx.z;
  int c0 = blockIdx.x * 32, r0 = blockIdx.y * 32;
  int tx = threadIdx.x & 31, ty = threadIdx.x >> 5;   // 32 x 8
  const float* inp = in + (size_t)e * R * C;
  unsigned short* op = out + (size_t)e * R * C;
  for (int i = 0; i < 4; ++i)
    tile[ty + i * 8][tx] = inp[(size_t)(r0 + ty + i * 8) * C + c0 + tx];
  __syncthreads();
  for (int i = 0; i < 4; ++i)
    op[(size_t)(c0 + ty + i * 8) * R + r0 + tx] = f2bf(tile[tx][ty + i * 8]);
}

// ---------------------------------------------------------------------------
// Gating: one wave per token. f64 logits (robust top-2 vs np ref), softmax
// over top-2 in f32, atomic slot assignment, fused x -> bf16 conversion.
// ---------------------------------------------------------------------------
__global__ __launch_bounds__(256) void gate_kernel(
    const float* __restrict__ x, const float* __restrict__ gw,
    unsigned short* __restrict__ xb, int* __restrict__ cnt,
    int* __restrict__ tIdx, int* __restrict__ tokEnc, float* __restrict__ tokW)
{
  int wv = threadIdx.x >> 6, lane = threadIdx.x & 63;
  int t = blockIdx.x * 4 + wv;
  const float* xrow = x + (size_t)t * DIM;

  float xs[16];
  const float4* x4 = (const float4*)xrow + lane * 4;
  for (int j = 0; j < 4; ++j) {
    float4 v = x4[j];
    xs[4 * j + 0] = v.x; xs[4 * j + 1] = v.y;
    xs[4 * j + 2] = v.z; xs[4 * j + 3] = v.w;
  }

  double acc[NE];
  for (int e = 0; e < NE; ++e) acc[e] = 0.0;
  for (int i = 0; i < 16; ++i) {
    int d = lane * 16 + i;
    const float4* g4 = (const float4*)(gw + (size_t)d * NE);
    float4 g0 = g4[0], g1 = g4[1];
    double xv = (double)xs[i];
    acc[0] += xv * (double)g0.x; acc[1] += xv * (double)g0.y;
    acc[2] += xv * (double)g0.z; acc[3] += xv * (double)g0.w;
    acc[4] += xv * (double)g1.x; acc[5] += xv * (double)g1.y;
    acc[6] += xv * (double)g1.z; acc[7] += xv * (double)g1.w;
  }

  // fused x -> bf16 (each lane owns 16 contiguous elements -> two uint4 stores)
  union { unsigned short us[16]; uint4 u4[2]; } cv;
  for (int i = 0; i < 16; ++i) cv.us[i] = f2bf(xs[i]);
  uint4* dst = (uint4*)(xb + (size_t)t * DIM + lane * 16);
  dst[0] = cv.u4[0]; dst[1] = cv.u4[1];

  // wave reduction of 8 logits
  for (int s = 32; s > 0; s >>= 1)
    for (int e = 0; e < NE; ++e)
      acc[e] += __shfl_down(acc[e], s, 64);

  if (lane == 0) {
    int e0 = 0; double v0 = acc[0];
    for (int e = 1; e < NE; ++e) if (acc[e] > v0) { v0 = acc[e]; e0 = e; }
    int e1 = -1; double v1 = -1.0e300;
    for (int e = 0; e < NE; ++e) {
      if (e == e0) continue;
      if (acc[e] > v1) { v1 = acc[e]; e1 = e; }
    }
    float a = (float)v0, b = (float)v1;
    float eb = __expf(b - a);
    float den = 1.0f + eb;
    float w0 = 1.0f / den, w1 = eb / den;
    int s0 = atomicAdd(&cnt[e0], 1);
    tIdx[e0 * T_TOK + s0] = t;
    tokEnc[2 * t + 0] = (e0 << 16) | s0;
    tokW[2 * t + 0] = w0;
    int s1 = atomicAdd(&cnt[e1], 1);
    tIdx[e1 * T_TOK + s1] = t;
    tokEnc[2 * t + 1] = (e1 << 16) | s1;
    tokW[2 * t + 1] = w1;
  }
}

__global__ void offsets_kernel(const int* __restrict__ cnt, int* __restrict__ off) {
  if (threadIdx.x == 0 && blockIdx.x == 0) {
    int a = 0;
    for (int e = 0; e < NE; ++e) { off[e] = a; a += cnt[e]; }
    off[NE] = a;
  }
}

// ---------------------------------------------------------------------------
// GEMM1: h[row][f] = silu( sum_d xb[tok(row)][d] * w1t[e][f][d] )   (bf16 out)
// 128x128 tile, BK=32, 4 waves, 16x16x32 bf16 MFMA, global_load_lds staging.
// LDS layout [kq][m][8]: fragment reads are single ds_read_b128, 2-way-free.
// ---------------------------------------------------------------------------
__global__ __launch_bounds__(256) void gemm1_kernel(
    const unsigned short* __restrict__ xb,   // [T][D] bf16
    const unsigned short* __restrict__ w1t,  // [E][F][D] bf16
    unsigned short* __restrict__ h,          // [2T][F] bf16 (compacted)
    const int* __restrict__ tIdx, const int* __restrict__ cnt,
    const int* __restrict__ off)
{
  int e = blockIdx.z;
  int count = cnt[e];
  int r0 = blockIdx.y * 128;
  if (r0 >= count) return;
  int n0 = blockIdx.x * 128;

  __shared__ __align__(16) unsigned short As[4][128][8];
  __shared__ __align__(16) unsigned short Bs[4][128][8];

  int tid = threadIdx.x, lane = tid & 63, w = tid >> 6;
  int wr = w >> 1, wc = w & 1;
  int quad = lane >> 4, li = lane & 15;

  const unsigned short* ag[2];
  const unsigned short* bg[2];
  for (int c = 0; c < 2; ++c) {
    int m = c * 64 + lane;
    int r = r0 + m; if (r > count - 1) r = count - 1;
    ag[c] = xb + (size_t)tIdx[e * T_TOK + r] * DIM + w * 8;
    bg[c] = w1t + ((size_t)e * FF + (n0 + m)) * DIM + w * 8;
  }

  floatx4 acc[4][4];
  for (int mi = 0; mi < 4; ++mi)
    for (int ni = 0; ni < 4; ++ni)
      for (int q = 0; q < 4; ++q) acc[mi][ni][q] = 0.0f;

  for (int k0 = 0; k0 < DIM; k0 += 32) {
    __syncthreads();
    gl_lds16(ag[0] + k0, &As[w][0][0]);
    gl_lds16(ag[1] + k0, &As[w][64][0]);
    gl_lds16(bg[0] + k0, &Bs[w][0][0]);
    gl_lds16(bg[1] + k0, &Bs[w][64][0]);
    __syncthreads();
    bf16x8 af[4], bf[4];
    for (int mi = 0; mi < 4; ++mi)
      af[mi] = *(const bf16x8*)&As[quad][wr * 64 + mi * 16 + li][0];
    for (int ni = 0; ni < 4; ++ni)
      bf[ni] = *(const bf16x8*)&Bs[quad][wc * 64 + ni * 16 + li][0];
    for (int mi = 0; mi < 4; ++mi)
      for (int ni = 0; ni < 4; ++ni)
        acc[mi][ni] = __builtin_amdgcn_mfma_f32_16x16x32_bf16(
            af[mi], bf[ni], acc[mi][ni], 0, 0, 0);
  }

  size_t hb = (size_t)off[e];
  for (int mi = 0; mi < 4; ++mi) {
    int rowb = wr * 64 + mi * 16 + quad * 4;
    for (int rr = 0; rr < 4; ++rr) {
      int r = r0 + rowb + rr;
      if (r >= count) continue;
      unsigned short* hrow = h + (hb + r) * FF + n0 + wc * 64 + li;
      for (int ni = 0; ni < 4; ++ni) {
        float v = acc[mi][ni][rr];
        float s = v / (1.0f + __expf(-v));   // silu
        hrow[ni * 16] = f2bf(s);
      }
    }
  }
}

// ---------------------------------------------------------------------------
// GEMM2: yv[row][d] = sum_f h[row][f] * w2t[e][d][f]    (f32 out, no atomics)
// ---------------------------------------------------------------------------
__global__ __launch_bounds__(256) void gemm2_kernel(
    const unsigned short* __restrict__ h,    // [2T][F] bf16
    const unsigned short* __restrict__ w2t,  // [E][D][F] bf16
    float* __restrict__ yv,                  // [2T][D] f32
    const int* __restrict__ cnt, const int* __restrict__ off)
{
  int e = blockIdx.z;
  int count = cnt[e];
  int r0 = blockIdx.y * 128;
  if (r0 >= count) return;
  int n0 = blockIdx.x * 128;

  __shared__ __align__(16) unsigned short As[4][128][8];
  __shared__ __align__(16) unsigned short Bs[4][128][8];

  int tid = threadIdx.x, lane = tid & 63, w = tid >> 6;
  int wr = w >> 1, wc = w & 1;
  int quad = lane >> 4, li = lane & 15;
  size_t yb = (size_t)off[e];

  const unsigned short* ag[2];
  const unsigned short* bg[2];
  for (int c = 0; c < 2; ++c) {
    int m = c * 64 + lane;
    int r = r0 + m; if (r > count - 1) r = count - 1;
    ag[c] = h + (yb + r) * FF + w * 8;
    bg[c] = w2t + ((size_t)e * DIM + (n0 + m)) * FF + w * 8;
  }

  floatx4 acc[4][4];
  for (int mi = 0; mi < 4; ++mi)
    for (int ni = 0; ni < 4; ++ni)
      for (int q = 0; q < 4; ++q) acc[mi][ni][q] = 0.0f;

  for (int k0 = 0; k0 < FF; k0 += 32) {
    __syncthreads();
    gl_lds16(ag[0] + k0, &As[w][0][0]);
    gl_lds16(ag[1] + k0, &As[w][64][0]);
    gl_lds16(bg[0] + k0, &Bs[w][0][0]);
    gl_lds16(bg[1] + k0, &Bs[w][64][0]);
    __syncthreads();
    bf16x8 af[4], bf[4];
    for (int mi = 0; mi < 4; ++mi)
      af[mi] = *(const bf16x8*)&As[quad][wr * 64 + mi * 16 + li][0];
    for (int ni = 0; ni < 4; ++ni)
      bf[ni] = *(const bf16x8*)&Bs[quad][wc * 64 + ni * 16 + li][0];
    for (int mi = 0; mi < 4; ++mi)
      for (int ni = 0; ni < 4; ++ni)
        acc[mi][ni] = __builtin_amdgcn_mfma_f32_16x16x32_bf16(
            af[mi], bf[ni], acc[mi][ni], 0, 0, 0);
  }

  for (int mi = 0; mi < 4; ++mi) {
    int rowb = wr * 64 + mi * 16 + quad * 4;
    for (int rr = 0; rr < 4; ++rr) {
      int r = r0 + rowb + rr;
      if (r >= count) continue;
      float* yrow = yv + (yb + r) * DIM + n0 + wc * 64 + li;
      for (int ni = 0; ni < 4; ++ni)
        yrow[ni * 16] = acc[mi][ni][rr];
    }
  }
}

// ---------------------------------------------------------------------------
// Combine: out[t] = w0 * yv[row0] + w1 * yv[row1]
// ---------------------------------------------------------------------------
__global__ __launch_bounds__(256) void combine_kernel(
    const float* __restrict__ yv, const int* __restrict__ tokEnc,
    const float* __restrict__ tokW, const int* __restrict__ off,
    float* __restrict__ out)
{
  int t = blockIdx.x;
  int i = threadIdx.x;   // 256 threads x float4 = 1024 = D
  int enc0 = tokEnc[2 * t + 0], enc1 = tokEnc[2 * t + 1];
  float w0 = tokW[2 * t + 0], w1 = tokW[2 * t + 1];
  size_t row0 = (size_t)off[enc0 >> 16] + (enc0 & 0xFFFF);
  size_t row1 = (size_t)off[enc1 >> 16] + (enc1 & 0xFFFF);
  float4 a = ((const float4*)(yv + row0 * DIM))[i];
  float4 b = ((const float4*)(yv + row1 * DIM))[i];
  float4 o;
  o.x = w0 * a.x + w1 * b.x;
  o.y = w0 * a.y + w1 * b.y;
  o.z = w0 * a.z + w1 * b.z;
  o.w = w0 * a.w + w1 * b.w;
  ((float4*)(out + (size_t)t * DIM))[i] = o;
}

// ---------------------------------------------------------------------------
extern "C" void kernel_launch(void* const* d_in, const int* in_sizes, int n_in,
                              void* d_out, int out_size, void* d_ws, size_t ws_size,
                              hipStream_t stream)
{
  const float* x  = (const float*)d_in[0];   // [T][D]
  const float* gw = (const float*)d_in[1];   // [D][E]
  const float* w1 = (const float*)d_in[2];   // [E][D][F]
  const float* w2 = (const float*)d_in[3];   // [E][F][D]
  float* out = (float*)d_out;                // [T][D]

  // workspace carve-up (256B aligned)
  size_t o = 0;
  auto alloc = [&](size_t bytes) {
    void* p = (char*)d_ws + o;
    o += (bytes + 255) & ~(size_t)255;
    return p;
  };
  unsigned short* xb   = (unsigned short*)alloc((size_t)T_TOK * DIM * 2);      // 16.8 MB
  unsigned short* w1t  = (unsigned short*)alloc((size_t)NE * DIM * FF * 2);    // 33.6 MB
  unsigned short* w2t  = (unsigned short*)alloc((size_t)NE * DIM * FF * 2);    // 33.6 MB
  unsigned short* hbuf = (unsigned short*)alloc((size_t)T_TOK * TOPK * FF * 2);// 67.1 MB
  float*          yv   = (float*)alloc((size_t)T_TOK * TOPK * DIM * 4);        // 67.1 MB
  int*   tIdx   = (int*)alloc((size_t)NE * T_TOK * 4);
  int*   tokEnc = (int*)alloc((size_t)2 * T_TOK * 4);
  float* tokW   = (float*)alloc((size_t)2 * T_TOK * 4);
  int*   cnt    = (int*)alloc((size_t)NE * 4);
  int*   off    = (int*)alloc((size_t)(NE + 1) * 4);

  hipMemsetAsync(cnt, 0, NE * sizeof(int), stream);

  // w1 [E][D][F] -> w1t [E][F][D] ; w2 [E][F][D] -> w2t [E][D][F]
  transpose_bf16_kernel<<<dim3(FF / 32, DIM / 32, NE), 256, 0, stream>>>(w1, w1t, DIM, FF);
  transpose_bf16_kernel<<<dim3(DIM / 32, FF / 32, NE), 256, 0, stream>>>(w2, w2t, FF, DIM);

  gate_kernel<<<T_TOK / 4, 256, 0, stream>>>(x, gw, xb, cnt, tIdx, tokEnc, tokW);
  offsets_kernel<<<1, 64, 0, stream>>>(cnt, off);

  gemm1_kernel<<<dim3(FF / 128, T_TOK / 128, NE), 256, 0, stream>>>(
      xb, w1t, hbuf, tIdx, cnt, off);
  gemm2_kernel<<<dim3(DIM / 128, T_TOK / 128, NE), 256, 0, stream>>>(
      hbuf, w2t, yv, cnt, off);
  combine_kernel<<<T_TOK, 256, 0, stream>>>(yv, tokEnc, tokW, off, out);
}

// Round 2
// 638.730 us; speedup vs baseline: 1.1856x; 1.1856x over previous
//
#include <hip/hip_runtime.h>
#include <cstdint>
#include <cstddef>

// Problem constants (B=2, S=4096 -> T=8192 tokens)
#define T_TOK 8192
#define DIM   1024   // D
#define NE    8      // experts
#define FF    2048   // F
#define TOPK  2

typedef __bf16 bf16x8 __attribute__((ext_vector_type(8)));
typedef float  floatx4 __attribute__((ext_vector_type(4)));

__device__ __forceinline__ unsigned short f2bf(float f) {
  unsigned int u = __float_as_uint(f);
  unsigned int r = 0x7FFFu + ((u >> 16) & 1u);   // round-to-nearest-even
  return (unsigned short)((u + r) >> 16);
}

__device__ __forceinline__ void gl_lds16(const void* g, void* l) {
  __builtin_amdgcn_global_load_lds(
      (__attribute__((address_space(1))) void*)g,
      (__attribute__((address_space(3))) void*)l,
      16, 0, 0);
}

// ---------------------------------------------------------------------------
// Transpose + f32->bf16 convert:  in[e][r][c] (f32) -> out[e][c][r] (bf16)
// ---------------------------------------------------------------------------
__global__ __launch_bounds__(256) void transpose_bf16_kernel(
    const float* __restrict__ in, unsigned short* __restrict__ out,
    int R, int C)
{
  __shared__ float tile[32][33];
  int e  = blockIdx.z;
  int c0 = blockIdx.x * 32, r0 = blockIdx.y * 32;
  int tx = threadIdx.x & 31, ty = threadIdx.x >> 5;   // 32 x 8
  const float* inp = in + (size_t)e * R * C;
  unsigned short* op = out + (size_t)e * R * C;
  for (int i = 0; i < 4; ++i)
    tile[ty + i * 8][tx] = inp[(size_t)(r0 + ty + i * 8) * C + c0 + tx];
  __syncthreads();
  for (int i = 0; i < 4; ++i)
    op[(size_t)(c0 + ty + i * 8) * R + r0 + tx] = f2bf(tile[tx][ty + i * 8]);
}

// ---------------------------------------------------------------------------
// Gating pass 1: one wave per token (4 waves/block). gw staged TRANSPOSED in
// LDS (gwT[e][d]) so the dot loop is conflict-free ds_read_b128. f64 logit
// accumulation (top-2 selection robust vs np ref). No atomics. Fused x->bf16.
// Writes tokExp[t] = e0 | (e1<<8) and tokW[2t..].
// ---------------------------------------------------------------------------
__global__ __launch_bounds__(256) void gate_kernel(
    const float* __restrict__ x, const float* __restrict__ gw,
    unsigned short* __restrict__ xb, int* __restrict__ tokExp,
    float* __restrict__ tokW)
{
  __shared__ float gwT[NE][DIM];   // 32 KB
  int tid = threadIdx.x;
  for (int i = tid; i < DIM * NE; i += 256) {
    int d = i >> 3, e = i & 7;
    gwT[e][d] = gw[i];
  }
  __syncthreads();

  int wv = tid >> 6, lane = tid & 63;
  int t = blockIdx.x * 4 + wv;
  const float* xrow = x + (size_t)t * DIM;
  unsigned short* xbrow = xb + (size_t)t * DIM;

  double acc[NE];
  for (int e = 0; e < NE; ++e) acc[e] = 0.0;

  for (int j = 0; j < 4; ++j) {
    float4 xv = ((const float4*)xrow)[j * 64 + lane];
    // fused bf16 conversion: contiguous 8B/lane stores
    ushort4 s;
    s.x = f2bf(xv.x); s.y = f2bf(xv.y); s.z = f2bf(xv.z); s.w = f2bf(xv.w);
    ((ushort4*)xbrow)[j * 64 + lane] = s;
    double xd0 = (double)xv.x, xd1 = (double)xv.y;
    double xd2 = (double)xv.z, xd3 = (double)xv.w;
    for (int e = 0; e < NE; ++e) {
      float4 g = ((const float4*)&gwT[e][0])[j * 64 + lane];
      acc[e] += xd0 * (double)g.x + xd1 * (double)g.y +
                xd2 * (double)g.z + xd3 * (double)g.w;
    }
  }

  // wave reduction of 8 logits
  for (int s = 32; s > 0; s >>= 1)
    for (int e = 0; e < NE; ++e)
      acc[e] += __shfl_down(acc[e], s, 64);

  if (lane == 0) {
    int e0 = 0; double v0 = acc[0];
    for (int e = 1; e < NE; ++e) if (acc[e] > v0) { v0 = acc[e]; e0 = e; }
    int e1 = -1; double v1 = -1.0e300;
    for (int e = 0; e < NE; ++e) {
      if (e == e0) continue;
      if (acc[e] > v1) { v1 = acc[e]; e1 = e; }
    }
    float a = (float)v0, b = (float)v1;
    float eb = __expf(b - a);
    float den = 1.0f + eb;
    tokExp[t] = e0 | (e1 << 8);
    tokW[2 * t + 0] = 1.0f / den;
    tokW[2 * t + 1] = eb / den;
  }
}

// ---------------------------------------------------------------------------
// Gating pass 2: slot assignment with ZERO atomics. One wave, ballot+popcount
// prefix counting; running per-expert bases are wave-uniform (ballot results
// are uniform). Also emits cnt[] and off[] (absorbs old offsets_kernel).
// ---------------------------------------------------------------------------
__global__ __launch_bounds__(64) void assign_kernel(
    const int* __restrict__ tokExp, int* __restrict__ tokEnc,
    int* __restrict__ tIdx, int* __restrict__ cnt, int* __restrict__ off)
{
  int lane = threadIdx.x;
  unsigned long long below = (1ull << lane) - 1ull;
  int base[NE];
  for (int e = 0; e < NE; ++e) base[e] = 0;

  for (int it = 0; it < T_TOK / 64; ++it) {
    int t = it * 64 + lane;
    int enc = tokExp[t];
    int e0 = enc & 0xFF, e1 = (enc >> 8) & 0xFF;
    int s0 = 0, s1 = 0;
    for (int e = 0; e < NE; ++e) {
      unsigned long long m0 = __ballot(e0 == e);
      unsigned long long m1 = __ballot(e1 == e);
      if (e0 == e) s0 = base[e] + __popcll(m0 & below);
      if (e1 == e) s1 = base[e] + __popcll(m0) + __popcll(m1 & below);
      base[e] += __popcll(m0) + __popcll(m1);
    }
    tokEnc[2 * t + 0] = (e0 << 16) | s0;
    tokEnc[2 * t + 1] = (e1 << 16) | s1;
    tIdx[e0 * T_TOK + s0] = t;
    tIdx[e1 * T_TOK + s1] = t;
  }

  if (lane == 0) {
    int a = 0;
    for (int e = 0; e < NE; ++e) { cnt[e] = base[e]; off[e] = a; a += base[e]; }
    off[NE] = a;
  }
}

// ---------------------------------------------------------------------------
// GEMM1: h[row][f] = silu( sum_d xb[tok(row)][d] * w1t[e][f][d] )   (bf16 out)
// 128x128 tile, BK=32, 4 waves, 16x16x32 bf16 MFMA, global_load_lds staging.
// LDS layout [kq][m][8]: fragment reads are single ds_read_b128, 2-way-free.
// ---------------------------------------------------------------------------
__global__ __launch_bounds__(256) void gemm1_kernel(
    const unsigned short* __restrict__ xb,   // [T][D] bf16
    const unsigned short* __restrict__ w1t,  // [E][F][D] bf16
    unsigned short* __restrict__ h,          // [2T][F] bf16 (compacted)
    const int* __restrict__ tIdx, const int* __restrict__ cnt,
    const int* __restrict__ off)
{
  int e = blockIdx.z;
  int count = cnt[e];
  int r0 = blockIdx.y * 128;
  if (r0 >= count) return;
  int n0 = blockIdx.x * 128;

  __shared__ __align__(16) unsigned short As[4][128][8];
  __shared__ __align__(16) unsigned short Bs[4][128][8];

  int tid = threadIdx.x, lane = tid & 63, w = tid >> 6;
  int wr = w >> 1, wc = w & 1;
  int quad = lane >> 4, li = lane & 15;

  const unsigned short* ag[2];
  const unsigned short* bg[2];
  for (int c = 0; c < 2; ++c) {
    int m = c * 64 + lane;
    int r = r0 + m; if (r > count - 1) r = count - 1;
    ag[c] = xb + (size_t)tIdx[e * T_TOK + r] * DIM + w * 8;
    bg[c] = w1t + ((size_t)e * FF + (n0 + m)) * DIM + w * 8;
  }

  floatx4 acc[4][4];
  for (int mi = 0; mi < 4; ++mi)
    for (int ni = 0; ni < 4; ++ni)
      for (int q = 0; q < 4; ++q) acc[mi][ni][q] = 0.0f;

  for (int k0 = 0; k0 < DIM; k0 += 32) {
    __syncthreads();
    gl_lds16(ag[0] + k0, &As[w][0][0]);
    gl_lds16(ag[1] + k0, &As[w][64][0]);
    gl_lds16(bg[0] + k0, &Bs[w][0][0]);
    gl_lds16(bg[1] + k0, &Bs[w][64][0]);
    __syncthreads();
    bf16x8 af[4], bf[4];
    for (int mi = 0; mi < 4; ++mi)
      af[mi] = *(const bf16x8*)&As[quad][wr * 64 + mi * 16 + li][0];
    for (int ni = 0; ni < 4; ++ni)
      bf[ni] = *(const bf16x8*)&Bs[quad][wc * 64 + ni * 16 + li][0];
    for (int mi = 0; mi < 4; ++mi)
      for (int ni = 0; ni < 4; ++ni)
        acc[mi][ni] = __builtin_amdgcn_mfma_f32_16x16x32_bf16(
            af[mi], bf[ni], acc[mi][ni], 0, 0, 0);
  }

  size_t hb = (size_t)off[e];
  for (int mi = 0; mi < 4; ++mi) {
    int rowb = wr * 64 + mi * 16 + quad * 4;
    for (int rr = 0; rr < 4; ++rr) {
      int r = r0 + rowb + rr;
      if (r >= count) continue;
      unsigned short* hrow = h + (hb + r) * FF + n0 + wc * 64 + li;
      for (int ni = 0; ni < 4; ++ni) {
        float v = acc[mi][ni][rr];
        float s = v / (1.0f + __expf(-v));   // silu
        hrow[ni * 16] = f2bf(s);
      }
    }
  }
}

// ---------------------------------------------------------------------------
// GEMM2: yv[row][d] = sum_f h[row][f] * w2t[e][d][f]    (f32 out, no atomics)
// ---------------------------------------------------------------------------
__global__ __launch_bounds__(256) void gemm2_kernel(
    const unsigned short* __restrict__ h,    // [2T][F] bf16
    const unsigned short* __restrict__ w2t,  // [E][D][F] bf16
    float* __restrict__ yv,                  // [2T][D] f32
    const int* __restrict__ cnt, const int* __restrict__ off)
{
  int e = blockIdx.z;
  int count = cnt[e];
  int r0 = blockIdx.y * 128;
  if (r0 >= count) return;
  int n0 = blockIdx.x * 128;

  __shared__ __align__(16) unsigned short As[4][128][8];
  __shared__ __align__(16) unsigned short Bs[4][128][8];

  int tid = threadIdx.x, lane = tid & 63, w = tid >> 6;
  int wr = w >> 1, wc = w & 1;
  int quad = lane >> 4, li = lane & 15;
  size_t yb = (size_t)off[e];

  const unsigned short* ag[2];
  const unsigned short* bg[2];
  for (int c = 0; c < 2; ++c) {
    int m = c * 64 + lane;
    int r = r0 + m; if (r > count - 1) r = count - 1;
    ag[c] = h + (yb + r) * FF + w * 8;
    bg[c] = w2t + ((size_t)e * DIM + (n0 + m)) * FF + w * 8;
  }

  floatx4 acc[4][4];
  for (int mi = 0; mi < 4; ++mi)
    for (int ni = 0; ni < 4; ++ni)
      for (int q = 0; q < 4; ++q) acc[mi][ni][q] = 0.0f;

  for (int k0 = 0; k0 < FF; k0 += 32) {
    __syncthreads();
    gl_lds16(ag[0] + k0, &As[w][0][0]);
    gl_lds16(ag[1] + k0, &As[w][64][0]);
    gl_lds16(bg[0] + k0, &Bs[w][0][0]);
    gl_lds16(bg[1] + k0, &Bs[w][64][0]);
    __syncthreads();
    bf16x8 af[4], bf[4];
    for (int mi = 0; mi < 4; ++mi)
      af[mi] = *(const bf16x8*)&As[quad][wr * 64 + mi * 16 + li][0];
    for (int ni = 0; ni < 4; ++ni)
      bf[ni] = *(const bf16x8*)&Bs[quad][wc * 64 + ni * 16 + li][0];
    for (int mi = 0; mi < 4; ++mi)
      for (int ni = 0; ni < 4; ++ni)
        acc[mi][ni] = __builtin_amdgcn_mfma_f32_16x16x32_bf16(
            af[mi], bf[ni], acc[mi][ni], 0, 0, 0);
  }

  for (int mi = 0; mi < 4; ++mi) {
    int rowb = wr * 64 + mi * 16 + quad * 4;
    for (int rr = 0; rr < 4; ++rr) {
      int r = r0 + rowb + rr;
      if (r >= count) continue;
      float* yrow = yv + (yb + r) * DIM + n0 + wc * 64 + li;
      for (int ni = 0; ni < 4; ++ni)
        yrow[ni * 16] = acc[mi][ni][rr];
    }
  }
}

// ---------------------------------------------------------------------------
// Combine: out[t] = w0 * yv[row0] + w1 * yv[row1]
// ---------------------------------------------------------------------------
__global__ __launch_bounds__(256) void combine_kernel(
    const float* __restrict__ yv, const int* __restrict__ tokEnc,
    const float* __restrict__ tokW, const int* __restrict__ off,
    float* __restrict__ out)
{
  int t = blockIdx.x;
  int i = threadIdx.x;   // 256 threads x float4 = 1024 = D
  int enc0 = tokEnc[2 * t + 0], enc1 = tokEnc[2 * t + 1];
  float w0 = tokW[2 * t + 0], w1 = tokW[2 * t + 1];
  size_t row0 = (size_t)off[enc0 >> 16] + (enc0 & 0xFFFF);
  size_t row1 = (size_t)off[enc1 >> 16] + (enc1 & 0xFFFF);
  float4 a = ((const float4*)(yv + row0 * DIM))[i];
  float4 b = ((const float4*)(yv + row1 * DIM))[i];
  float4 o;
  o.x = w0 * a.x + w1 * b.x;
  o.y = w0 * a.y + w1 * b.y;
  o.z = w0 * a.z + w1 * b.z;
  o.w = w0 * a.w + w1 * b.w;
  ((float4*)(out + (size_t)t * DIM))[i] = o;
}

// ---------------------------------------------------------------------------
extern "C" void kernel_launch(void* const* d_in, const int* in_sizes, int n_in,
                              void* d_out, int out_size, void* d_ws, size_t ws_size,
                              hipStream_t stream)
{
  const float* x  = (const float*)d_in[0];   // [T][D]
  const float* gw = (const float*)d_in[1];   // [D][E]
  const float* w1 = (const float*)d_in[2];   // [E][D][F]
  const float* w2 = (const float*)d_in[3];   // [E][F][D]
  float* out = (float*)d_out;                // [T][D]

  // workspace carve-up (256B aligned)
  size_t o = 0;
  auto alloc = [&](size_t bytes) {
    void* p = (char*)d_ws + o;
    o += (bytes + 255) & ~(size_t)255;
    return p;
  };
  unsigned short* xb   = (unsigned short*)alloc((size_t)T_TOK * DIM * 2);      // 16.8 MB
  unsigned short* w1t  = (unsigned short*)alloc((size_t)NE * DIM * FF * 2);    // 33.6 MB
  unsigned short* w2t  = (unsigned short*)alloc((size_t)NE * DIM * FF * 2);    // 33.6 MB
  unsigned short* hbuf = (unsigned short*)alloc((size_t)T_TOK * TOPK * FF * 2);// 67.1 MB
  float*          yv   = (float*)alloc((size_t)T_TOK * TOPK * DIM * 4);        // 67.1 MB
  int*   tIdx   = (int*)alloc((size_t)NE * T_TOK * 4);
  int*   tokEnc = (int*)alloc((size_t)2 * T_TOK * 4);
  float* tokW   = (float*)alloc((size_t)2 * T_TOK * 4);
  int*   tokExp = (int*)alloc((size_t)T_TOK * 4);
  int*   cnt    = (int*)alloc((size_t)NE * 4);
  int*   off    = (int*)alloc((size_t)(NE + 1) * 4);

  // w1 [E][D][F] -> w1t [E][F][D] ; w2 [E][F][D] -> w2t [E][D][F]
  transpose_bf16_kernel<<<dim3(FF / 32, DIM / 32, NE), 256, 0, stream>>>(w1, w1t, DIM, FF);
  transpose_bf16_kernel<<<dim3(DIM / 32, FF / 32, NE), 256, 0, stream>>>(w2, w2t, FF, DIM);

  gate_kernel<<<T_TOK / 4, 256, 0, stream>>>(x, gw, xb, tokExp, tokW);
  assign_kernel<<<1, 64, 0, stream>>>(tokExp, tokEnc, tIdx, cnt, off);

  gemm1_kernel<<<dim3(FF / 128, T_TOK / 128, NE), 256, 0, stream>>>(
      xb, w1t, hbuf, tIdx, cnt, off);
  gemm2_kernel<<<dim3(DIM / 128, T_TOK / 128, NE), 256, 0, stream>>>(
      hbuf, w2t, yv, cnt, off);
  combine_kernel<<<T_TOK, 256, 0, stream>>>(yv, tokEnc, tokW, off, out);
}

// Round 3
// 624.744 us; speedup vs baseline: 1.2121x; 1.0224x over previous
//
#include <hip/hip_runtime.h>
#include <cstdint>
#include <cstddef>

// Problem constants (B=2, S=4096 -> T=8192 tokens)
#define T_TOK 8192
#define DIM   1024   // D
#define NE    8      // experts
#define FF    2048   // F
#define TOPK  2

typedef __bf16 bf16x8 __attribute__((ext_vector_type(8)));
typedef float  floatx4 __attribute__((ext_vector_type(4)));

__device__ __forceinline__ unsigned short f2bf(float f) {
  unsigned int u = __float_as_uint(f);
  unsigned int r = 0x7FFFu + ((u >> 16) & 1u);   // round-to-nearest-even
  return (unsigned short)((u + r) >> 16);
}

__device__ __forceinline__ void gl_lds16(const void* g, void* l) {
  __builtin_amdgcn_global_load_lds(
      (__attribute__((address_space(1))) void*)g,
      (__attribute__((address_space(3))) void*)l,
      16, 0, 0);
}

// ---------------------------------------------------------------------------
// Transpose + f32->bf16 convert:  in[e][r][c] (f32) -> out[e][c][r] (bf16)
// ---------------------------------------------------------------------------
__global__ __launch_bounds__(256) void transpose_bf16_kernel(
    const float* __restrict__ in, unsigned short* __restrict__ out,
    int R, int C)
{
  __shared__ float tile[32][33];
  int e  = blockIdx.z;
  int c0 = blockIdx.x * 32, r0 = blockIdx.y * 32;
  int tx = threadIdx.x & 31, ty = threadIdx.x >> 5;   // 32 x 8
  const float* inp = in + (size_t)e * R * C;
  unsigned short* op = out + (size_t)e * R * C;
  for (int i = 0; i < 4; ++i)
    tile[ty + i * 8][tx] = inp[(size_t)(r0 + ty + i * 8) * C + c0 + tx];
  __syncthreads();
  for (int i = 0; i < 4; ++i)
    op[(size_t)(c0 + ty + i * 8) * R + r0 + tx] = f2bf(tile[tx][ty + i * 8]);
}

// ---------------------------------------------------------------------------
// Gating pass 1: one wave per token (4 waves/block). gw staged TRANSPOSED in
// LDS (gwT[e][d]) so the dot loop is conflict-free ds_read_b128. f64 logit
// accumulation (top-2 selection robust vs np ref). No atomics. Fused x->bf16.
// ---------------------------------------------------------------------------
__global__ __launch_bounds__(256) void gate_kernel(
    const float* __restrict__ x, const float* __restrict__ gw,
    unsigned short* __restrict__ xb, int* __restrict__ tokExp,
    float* __restrict__ tokW)
{
  __shared__ float gwT[NE][DIM];   // 32 KB
  int tid = threadIdx.x;
  for (int i = tid; i < DIM * NE; i += 256) {
    int d = i >> 3, e = i & 7;
    gwT[e][d] = gw[i];
  }
  __syncthreads();

  int wv = tid >> 6, lane = tid & 63;
  int t = blockIdx.x * 4 + wv;
  const float* xrow = x + (size_t)t * DIM;
  unsigned short* xbrow = xb + (size_t)t * DIM;

  double acc[NE];
  for (int e = 0; e < NE; ++e) acc[e] = 0.0;

  for (int j = 0; j < 4; ++j) {
    float4 xv = ((const float4*)xrow)[j * 64 + lane];
    ushort4 s;
    s.x = f2bf(xv.x); s.y = f2bf(xv.y); s.z = f2bf(xv.z); s.w = f2bf(xv.w);
    ((ushort4*)xbrow)[j * 64 + lane] = s;
    double xd0 = (double)xv.x, xd1 = (double)xv.y;
    double xd2 = (double)xv.z, xd3 = (double)xv.w;
    for (int e = 0; e < NE; ++e) {
      float4 g = ((const float4*)&gwT[e][0])[j * 64 + lane];
      acc[e] += xd0 * (double)g.x + xd1 * (double)g.y +
                xd2 * (double)g.z + xd3 * (double)g.w;
    }
  }

  for (int s = 32; s > 0; s >>= 1)
    for (int e = 0; e < NE; ++e)
      acc[e] += __shfl_down(acc[e], s, 64);

  if (lane == 0) {
    int e0 = 0; double v0 = acc[0];
    for (int e = 1; e < NE; ++e) if (acc[e] > v0) { v0 = acc[e]; e0 = e; }
    int e1 = -1; double v1 = -1.0e300;
    for (int e = 0; e < NE; ++e) {
      if (e == e0) continue;
      if (acc[e] > v1) { v1 = acc[e]; e1 = e; }
    }
    float a = (float)v0, b = (float)v1;
    float eb = __expf(b - a);
    float den = 1.0f + eb;
    tokExp[t] = e0 | (e1 << 8);
    tokW[2 * t + 0] = 1.0f / den;
    tokW[2 * t + 1] = eb / den;
  }
}

// ---------------------------------------------------------------------------
// Gating pass 2: slot assignment with ZERO atomics (ballot+popcount prefix).
// ---------------------------------------------------------------------------
__global__ __launch_bounds__(64) void assign_kernel(
    const int* __restrict__ tokExp, int* __restrict__ tokEnc,
    int* __restrict__ tIdx, int* __restrict__ cnt, int* __restrict__ off)
{
  int lane = threadIdx.x;
  unsigned long long below = (1ull << lane) - 1ull;
  int base[NE];
  for (int e = 0; e < NE; ++e) base[e] = 0;

  for (int it = 0; it < T_TOK / 64; ++it) {
    int t = it * 64 + lane;
    int enc = tokExp[t];
    int e0 = enc & 0xFF, e1 = (enc >> 8) & 0xFF;
    int s0 = 0, s1 = 0;
    for (int e = 0; e < NE; ++e) {
      unsigned long long m0 = __ballot(e0 == e);
      unsigned long long m1 = __ballot(e1 == e);
      if (e0 == e) s0 = base[e] + __popcll(m0 & below);
      if (e1 == e) s1 = base[e] + __popcll(m0) + __popcll(m1 & below);
      base[e] += __popcll(m0) + __popcll(m1);
    }
    tokEnc[2 * t + 0] = (e0 << 16) | s0;
    tokEnc[2 * t + 1] = (e1 << 16) | s1;
    tIdx[e0 * T_TOK + s0] = t;
    tIdx[e1 * T_TOK + s1] = t;
  }

  if (lane == 0) {
    int a = 0;
    for (int e = 0; e < NE; ++e) { cnt[e] = base[e]; off[e] = a; a += base[e]; }
    off[NE] = a;
  }
}

// ---------------------------------------------------------------------------
// GEMM1: h[row][f] = silu( sum_d xb[tok(row)][d] * w1t[e][f][d] )   (bf16 out)
// 128x128 tile, BK=64 (2x MFMA per barrier drain vs BK=32), 4 waves,
// 16x16x32 bf16 MFMA, global_load_lds width-16 staging.
// LDS [kq][m][8]: fragment reads are single ds_read_b128, 2-way-free.
// ---------------------------------------------------------------------------
__global__ __launch_bounds__(256, 4) void gemm1_kernel(
    const unsigned short* __restrict__ xb,   // [T][D] bf16
    const unsigned short* __restrict__ w1t,  // [E][F][D] bf16
    unsigned short* __restrict__ h,          // [2T][F] bf16 (compacted)
    const int* __restrict__ tIdx, const int* __restrict__ cnt,
    const int* __restrict__ off)
{
  int e = blockIdx.z;
  int count = cnt[e];
  int r0 = blockIdx.y * 128;
  if (r0 >= count) return;
  int n0 = blockIdx.x * 128;

  __shared__ __align__(16) unsigned short As[8][128][8];   // 16 KB
  __shared__ __align__(16) unsigned short Bs[8][128][8];   // 16 KB

  int tid = threadIdx.x, lane = tid & 63, w = tid >> 6;
  int wr = w >> 1, wc = w & 1;
  int quad = lane >> 4, li = lane & 15;

  const unsigned short* ag[2];
  const unsigned short* bg[2];
  for (int c = 0; c < 2; ++c) {
    int m = c * 64 + lane;
    int r = r0 + m; if (r > count - 1) r = count - 1;
    ag[c] = xb + (size_t)tIdx[e * T_TOK + r] * DIM;
    bg[c] = w1t + ((size_t)e * FF + (n0 + m)) * DIM;
  }

  floatx4 acc[4][4];
  for (int mi = 0; mi < 4; ++mi)
    for (int ni = 0; ni < 4; ++ni)
      for (int q = 0; q < 4; ++q) acc[mi][ni][q] = 0.0f;

  for (int k0 = 0; k0 < DIM; k0 += 64) {
    __syncthreads();
    for (int kk = 0; kk < 2; ++kk) {
      int kq = w + kk * 4;
      gl_lds16(ag[0] + k0 + kq * 8, &As[kq][0][0]);
      gl_lds16(ag[1] + k0 + kq * 8, &As[kq][64][0]);
      gl_lds16(bg[0] + k0 + kq * 8, &Bs[kq][0][0]);
      gl_lds16(bg[1] + k0 + kq * 8, &Bs[kq][64][0]);
    }
    __syncthreads();
    for (int ks = 0; ks < 2; ++ks) {
      bf16x8 af[4], bf[4];
      for (int mi = 0; mi < 4; ++mi)
        af[mi] = *(const bf16x8*)&As[ks * 4 + quad][wr * 64 + mi * 16 + li][0];
      for (int ni = 0; ni < 4; ++ni)
        bf[ni] = *(const bf16x8*)&Bs[ks * 4 + quad][wc * 64 + ni * 16 + li][0];
      for (int mi = 0; mi < 4; ++mi)
        for (int ni = 0; ni < 4; ++ni)
          acc[mi][ni] = __builtin_amdgcn_mfma_f32_16x16x32_bf16(
              af[mi], bf[ni], acc[mi][ni], 0, 0, 0);
    }
  }

  size_t hb = (size_t)off[e];
  for (int mi = 0; mi < 4; ++mi) {
    int rowb = wr * 64 + mi * 16 + quad * 4;
    for (int rr = 0; rr < 4; ++rr) {
      int r = r0 + rowb + rr;
      if (r >= count) continue;
      unsigned short* hrow = h + (hb + r) * FF + n0 + wc * 64 + li;
      for (int ni = 0; ni < 4; ++ni) {
        float v = acc[mi][ni][rr];
        float s = v / (1.0f + __expf(-v));   // silu
        hrow[ni * 16] = f2bf(s);
      }
    }
  }
}

// ---------------------------------------------------------------------------
// GEMM2: yv[row][d] = sum_f h[row][f] * w2t[e][d][f]    (f32 out, no atomics)
// Same BK=64 structure.
// ---------------------------------------------------------------------------
__global__ __launch_bounds__(256, 4) void gemm2_kernel(
    const unsigned short* __restrict__ h,    // [2T][F] bf16
    const unsigned short* __restrict__ w2t,  // [E][D][F] bf16
    float* __restrict__ yv,                  // [2T][D] f32
    const int* __restrict__ cnt, const int* __restrict__ off)
{
  int e = blockIdx.z;
  int count = cnt[e];
  int r0 = blockIdx.y * 128;
  if (r0 >= count) return;
  int n0 = blockIdx.x * 128;

  __shared__ __align__(16) unsigned short As[8][128][8];   // 16 KB
  __shared__ __align__(16) unsigned short Bs[8][128][8];   // 16 KB

  int tid = threadIdx.x, lane = tid & 63, w = tid >> 6;
  int wr = w >> 1, wc = w & 1;
  int quad = lane >> 4, li = lane & 15;
  size_t yb = (size_t)off[e];

  const unsigned short* ag[2];
  const unsigned short* bg[2];
  for (int c = 0; c < 2; ++c) {
    int m = c * 64 + lane;
    int r = r0 + m; if (r > count - 1) r = count - 1;
    ag[c] = h + (yb + r) * FF;
    bg[c] = w2t + ((size_t)e * DIM + (n0 + m)) * FF;
  }

  floatx4 acc[4][4];
  for (int mi = 0; mi < 4; ++mi)
    for (int ni = 0; ni < 4; ++ni)
      for (int q = 0; q < 4; ++q) acc[mi][ni][q] = 0.0f;

  for (int k0 = 0; k0 < FF; k0 += 64) {
    __syncthreads();
    for (int kk = 0; kk < 2; ++kk) {
      int kq = w + kk * 4;
      gl_lds16(ag[0] + k0 + kq * 8, &As[kq][0][0]);
      gl_lds16(ag[1] + k0 + kq * 8, &As[kq][64][0]);
      gl_lds16(bg[0] + k0 + kq * 8, &Bs[kq][0][0]);
      gl_lds16(bg[1] + k0 + kq * 8, &Bs[kq][64][0]);
    }
    __syncthreads();
    for (int ks = 0; ks < 2; ++ks) {
      bf16x8 af[4], bf[4];
      for (int mi = 0; mi < 4; ++mi)
        af[mi] = *(const bf16x8*)&As[ks * 4 + quad][wr * 64 + mi * 16 + li][0];
      for (int ni = 0; ni < 4; ++ni)
        bf[ni] = *(const bf16x8*)&Bs[ks * 4 + quad][wc * 64 + ni * 16 + li][0];
      for (int mi = 0; mi < 4; ++mi)
        for (int ni = 0; ni < 4; ++ni)
          acc[mi][ni] = __builtin_amdgcn_mfma_f32_16x16x32_bf16(
              af[mi], bf[ni], acc[mi][ni], 0, 0, 0);
    }
  }

  for (int mi = 0; mi < 4; ++mi) {
    int rowb = wr * 64 + mi * 16 + quad * 4;
    for (int rr = 0; rr < 4; ++rr) {
      int r = r0 + rowb + rr;
      if (r >= count) continue;
      float* yrow = yv + (yb + r) * DIM + n0 + wc * 64 + li;
      for (int ni = 0; ni < 4; ++ni)
        yrow[ni * 16] = acc[mi][ni][rr];
    }
  }
}

// ---------------------------------------------------------------------------
// Combine: out[t] = w0 * yv[row0] + w1 * yv[row1]
// ---------------------------------------------------------------------------
__global__ __launch_bounds__(256) void combine_kernel(
    const float* __restrict__ yv, const int* __restrict__ tokEnc,
    const float* __restrict__ tokW, const int* __restrict__ off,
    float* __restrict__ out)
{
  int t = blockIdx.x;
  int i = threadIdx.x;   // 256 threads x float4 = 1024 = D
  int enc0 = tokEnc[2 * t + 0], enc1 = tokEnc[2 * t + 1];
  float w0 = tokW[2 * t + 0], w1 = tokW[2 * t + 1];
  size_t row0 = (size_t)off[enc0 >> 16] + (enc0 & 0xFFFF);
  size_t row1 = (size_t)off[enc1 >> 16] + (enc1 & 0xFFFF);
  float4 a = ((const float4*)(yv + row0 * DIM))[i];
  float4 b = ((const float4*)(yv + row1 * DIM))[i];
  float4 o;
  o.x = w0 * a.x + w1 * b.x;
  o.y = w0 * a.y + w1 * b.y;
  o.z = w0 * a.z + w1 * b.z;
  o.w = w0 * a.w + w1 * b.w;
  ((float4*)(out + (size_t)t * DIM))[i] = o;
}

// ---------------------------------------------------------------------------
extern "C" void kernel_launch(void* const* d_in, const int* in_sizes, int n_in,
                              void* d_out, int out_size, void* d_ws, size_t ws_size,
                              hipStream_t stream)
{
  const float* x  = (const float*)d_in[0];   // [T][D]
  const float* gw = (const float*)d_in[1];   // [D][E]
  const float* w1 = (const float*)d_in[2];   // [E][D][F]
  const float* w2 = (const float*)d_in[3];   // [E][F][D]
  float* out = (float*)d_out;                // [T][D]

  // workspace carve-up (256B aligned)
  size_t o = 0;
  auto alloc = [&](size_t bytes) {
    void* p = (char*)d_ws + o;
    o += (bytes + 255) & ~(size_t)255;
    return p;
  };
  unsigned short* xb   = (unsigned short*)alloc((size_t)T_TOK * DIM * 2);      // 16.8 MB
  unsigned short* w1t  = (unsigned short*)alloc((size_t)NE * DIM * FF * 2);    // 33.6 MB
  unsigned short* w2t  = (unsigned short*)alloc((size_t)NE * DIM * FF * 2);    // 33.6 MB
  unsigned short* hbuf = (unsigned short*)alloc((size_t)T_TOK * TOPK * FF * 2);// 67.1 MB
  float*          yv   = (float*)alloc((size_t)T_TOK * TOPK * DIM * 4);        // 67.1 MB
  int*   tIdx   = (int*)alloc((size_t)NE * T_TOK * 4);
  int*   tokEnc = (int*)alloc((size_t)2 * T_TOK * 4);
  float* tokW   = (float*)alloc((size_t)2 * T_TOK * 4);
  int*   tokExp = (int*)alloc((size_t)T_TOK * 4);
  int*   cnt    = (int*)alloc((size_t)NE * 4);
  int*   off    = (int*)alloc((size_t)(NE + 1) * 4);

  // w1 [E][D][F] -> w1t [E][F][D] ; w2 [E][F][D] -> w2t [E][D][F]
  transpose_bf16_kernel<<<dim3(FF / 32, DIM / 32, NE), 256, 0, stream>>>(w1, w1t, DIM, FF);
  transpose_bf16_kernel<<<dim3(DIM / 32, FF / 32, NE), 256, 0, stream>>>(w2, w2t, FF, DIM);

  gate_kernel<<<T_TOK / 4, 256, 0, stream>>>(x, gw, xb, tokExp, tokW);
  assign_kernel<<<1, 64, 0, stream>>>(tokExp, tokEnc, tIdx, cnt, off);

  gemm1_kernel<<<dim3(FF / 128, T_TOK / 128, NE), 256, 0, stream>>>(
      xb, w1t, hbuf, tIdx, cnt, off);
  gemm2_kernel<<<dim3(DIM / 128, T_TOK / 128, NE), 256, 0, stream>>>(
      hbuf, w2t, yv, cnt, off);
  combine_kernel<<<T_TOK, 256, 0, stream>>>(yv, tokEnc, tokW, off, out);
}

// Round 4
// 605.647 us; speedup vs baseline: 1.2503x; 1.0315x over previous
//
#include <hip/hip_runtime.h>
#include <cstdint>
#include <cstddef>

// Problem constants (B=2, S=4096 -> T=8192 tokens)
#define T_TOK 8192
#define DIM   1024   // D
#define NE    8      // experts
#define FF    2048   // F
#define TOPK  2

typedef __bf16 bf16x8 __attribute__((ext_vector_type(8)));
typedef float  floatx4 __attribute__((ext_vector_type(4)));

__device__ __forceinline__ unsigned short f2bf(float f) {
  unsigned int u = __float_as_uint(f);
  unsigned int r = 0x7FFFu + ((u >> 16) & 1u);   // round-to-nearest-even
  return (unsigned short)((u + r) >> 16);
}

__device__ __forceinline__ void gl_lds16(const void* g, void* l) {
  __builtin_amdgcn_global_load_lds(
      (__attribute__((address_space(1))) void*)g,
      (__attribute__((address_space(3))) void*)l,
      16, 0, 0);
}

// ---------------------------------------------------------------------------
// Transpose + f32->bf16 convert:  in[e][r][c] (f32) -> out[e][c][r] (bf16)
// ---------------------------------------------------------------------------
__global__ __launch_bounds__(256) void transpose_bf16_kernel(
    const float* __restrict__ in, unsigned short* __restrict__ out,
    int R, int C)
{
  __shared__ float tile[32][33];
  int e  = blockIdx.z;
  int c0 = blockIdx.x * 32, r0 = blockIdx.y * 32;
  int tx = threadIdx.x & 31, ty = threadIdx.x >> 5;   // 32 x 8
  const float* inp = in + (size_t)e * R * C;
  unsigned short* op = out + (size_t)e * R * C;
  for (int i = 0; i < 4; ++i)
    tile[ty + i * 8][tx] = inp[(size_t)(r0 + ty + i * 8) * C + c0 + tx];
  __syncthreads();
  for (int i = 0; i < 4; ++i)
    op[(size_t)(c0 + ty + i * 8) * R + r0 + tx] = f2bf(tile[tx][ty + i * 8]);
}

// ---------------------------------------------------------------------------
// Gating pass 1: one wave per token (4 waves/block). gw staged TRANSPOSED in
// LDS. f64 logit accumulation (top-2 robust vs np ref). Fused x->bf16.
// ---------------------------------------------------------------------------
__global__ __launch_bounds__(256) void gate_kernel(
    const float* __restrict__ x, const float* __restrict__ gw,
    unsigned short* __restrict__ xb, int* __restrict__ tokExp,
    float* __restrict__ tokW)
{
  __shared__ float gwT[NE][DIM];   // 32 KB
  int tid = threadIdx.x;
  for (int i = tid; i < DIM * NE; i += 256) {
    int d = i >> 3, e = i & 7;
    gwT[e][d] = gw[i];
  }
  __syncthreads();

  int wv = tid >> 6, lane = tid & 63;
  int t = blockIdx.x * 4 + wv;
  const float* xrow = x + (size_t)t * DIM;
  unsigned short* xbrow = xb + (size_t)t * DIM;

  double acc[NE];
  for (int e = 0; e < NE; ++e) acc[e] = 0.0;

  for (int j = 0; j < 4; ++j) {
    float4 xv = ((const float4*)xrow)[j * 64 + lane];
    ushort4 s;
    s.x = f2bf(xv.x); s.y = f2bf(xv.y); s.z = f2bf(xv.z); s.w = f2bf(xv.w);
    ((ushort4*)xbrow)[j * 64 + lane] = s;
    double xd0 = (double)xv.x, xd1 = (double)xv.y;
    double xd2 = (double)xv.z, xd3 = (double)xv.w;
    for (int e = 0; e < NE; ++e) {
      float4 g = ((const float4*)&gwT[e][0])[j * 64 + lane];
      acc[e] += xd0 * (double)g.x + xd1 * (double)g.y +
                xd2 * (double)g.z + xd3 * (double)g.w;
    }
  }

  for (int s = 32; s > 0; s >>= 1)
    for (int e = 0; e < NE; ++e)
      acc[e] += __shfl_down(acc[e], s, 64);

  if (lane == 0) {
    int e0 = 0; double v0 = acc[0];
    for (int e = 1; e < NE; ++e) if (acc[e] > v0) { v0 = acc[e]; e0 = e; }
    int e1 = -1; double v1 = -1.0e300;
    for (int e = 0; e < NE; ++e) {
      if (e == e0) continue;
      if (acc[e] > v1) { v1 = acc[e]; e1 = e; }
    }
    float a = (float)v0, b = (float)v1;
    float eb = __expf(b - a);
    float den = 1.0f + eb;
    tokExp[t] = e0 | (e1 << 8);
    tokW[2 * t + 0] = 1.0f / den;
    tokW[2 * t + 1] = eb / den;
  }
}

// ---------------------------------------------------------------------------
// Gating pass 2: slot assignment with ZERO atomics (ballot+popcount prefix).
// ---------------------------------------------------------------------------
__global__ __launch_bounds__(64) void assign_kernel(
    const int* __restrict__ tokExp, int* __restrict__ tokEnc,
    int* __restrict__ tIdx, int* __restrict__ cnt, int* __restrict__ off)
{
  int lane = threadIdx.x;
  unsigned long long below = (1ull << lane) - 1ull;
  int base[NE];
  for (int e = 0; e < NE; ++e) base[e] = 0;

  for (int it = 0; it < T_TOK / 64; ++it) {
    int t = it * 64 + lane;
    int enc = tokExp[t];
    int e0 = enc & 0xFF, e1 = (enc >> 8) & 0xFF;
    int s0 = 0, s1 = 0;
    for (int e = 0; e < NE; ++e) {
      unsigned long long m0 = __ballot(e0 == e);
      unsigned long long m1 = __ballot(e1 == e);
      if (e0 == e) s0 = base[e] + __popcll(m0 & below);
      if (e1 == e) s1 = base[e] + __popcll(m0) + __popcll(m1 & below);
      base[e] += __popcll(m0) + __popcll(m1);
    }
    tokEnc[2 * t + 0] = (e0 << 16) | s0;
    tokEnc[2 * t + 1] = (e1 << 16) | s1;
    tIdx[e0 * T_TOK + s0] = t;
    tIdx[e1 * T_TOK + s1] = t;
  }

  if (lane == 0) {
    int a = 0;
    for (int e = 0; e < NE; ++e) { cnt[e] = base[e]; off[e] = a; a += base[e]; }
    off[NE] = a;
  }
}

// ---------------------------------------------------------------------------
// GEMM1: h[row][f] = silu( sum_d xb[tok(row)][d] * w1t[e][f][d] )   (bf16 out)
// 128x128 tile, BK=64, 16x16x32 MFMA, global_load_lds width-16 staging.
// XCD-pinned 1-D launch: g&7 = XCD = expert; within XCD: phase(n-half) outer,
// m outer, n inner -> L2 working set = 2MB B-half + 256KB A-tile (<4MB L2).
// ---------------------------------------------------------------------------
__global__ __launch_bounds__(256, 4) void gemm1_kernel(
    const unsigned short* __restrict__ xb,   // [T][D] bf16
    const unsigned short* __restrict__ w1t,  // [E][F][D] bf16
    unsigned short* __restrict__ h,          // [2T][F] bf16 (compacted)
    const int* __restrict__ tIdx, const int* __restrict__ cnt,
    const int* __restrict__ off)
{
  // decode swizzled 1-D id: g = (phase*512 + m*8 + nl)*8 + e
  int g = blockIdx.x;
  int e = g & 7;
  int b = g >> 3;              // 0..1023
  int phase = b >> 9;          // 0..1  (n-half)
  int m = (b >> 3) & 63;       // 0..63 (M-tile)
  int nl = b & 7;              // 0..7  (n within half)
  int count = cnt[e];
  int r0 = m * 128;
  if (r0 >= count) return;
  int n0 = (phase * 8 + nl) * 128;

  __shared__ __align__(16) unsigned short As[8][128][8];   // 16 KB
  __shared__ __align__(16) unsigned short Bs[8][128][8];   // 16 KB

  int tid = threadIdx.x, lane = tid & 63, w = tid >> 6;
  int wr = w >> 1, wc = w & 1;
  int quad = lane >> 4, li = lane & 15;

  const unsigned short* ag[2];
  const unsigned short* bg[2];
  for (int c = 0; c < 2; ++c) {
    int mm = c * 64 + lane;
    int r = r0 + mm; if (r > count - 1) r = count - 1;
    ag[c] = xb + (size_t)tIdx[e * T_TOK + r] * DIM;
    bg[c] = w1t + ((size_t)e * FF + (n0 + mm)) * DIM;
  }

  floatx4 acc[4][4];
  for (int mi = 0; mi < 4; ++mi)
    for (int ni = 0; ni < 4; ++ni)
      for (int q = 0; q < 4; ++q) acc[mi][ni][q] = 0.0f;

  for (int k0 = 0; k0 < DIM; k0 += 64) {
    __syncthreads();
    for (int kk = 0; kk < 2; ++kk) {
      int kq = w + kk * 4;
      gl_lds16(ag[0] + k0 + kq * 8, &As[kq][0][0]);
      gl_lds16(ag[1] + k0 + kq * 8, &As[kq][64][0]);
      gl_lds16(bg[0] + k0 + kq * 8, &Bs[kq][0][0]);
      gl_lds16(bg[1] + k0 + kq * 8, &Bs[kq][64][0]);
    }
    __syncthreads();
    for (int ks = 0; ks < 2; ++ks) {
      bf16x8 af[4], bf[4];
      for (int mi = 0; mi < 4; ++mi)
        af[mi] = *(const bf16x8*)&As[ks * 4 + quad][wr * 64 + mi * 16 + li][0];
      for (int ni = 0; ni < 4; ++ni)
        bf[ni] = *(const bf16x8*)&Bs[ks * 4 + quad][wc * 64 + ni * 16 + li][0];
      for (int mi = 0; mi < 4; ++mi)
        for (int ni = 0; ni < 4; ++ni)
          acc[mi][ni] = __builtin_amdgcn_mfma_f32_16x16x32_bf16(
              af[mi], bf[ni], acc[mi][ni], 0, 0, 0);
    }
  }

  size_t hb = (size_t)off[e];
  for (int mi = 0; mi < 4; ++mi) {
    int rowb = wr * 64 + mi * 16 + quad * 4;
    for (int rr = 0; rr < 4; ++rr) {
      int r = r0 + rowb + rr;
      if (r >= count) continue;
      unsigned short* hrow = h + (hb + r) * FF + n0 + wc * 64 + li;
      for (int ni = 0; ni < 4; ++ni) {
        float v = acc[mi][ni][rr];
        float s = v / (1.0f + __expf(-v));   // silu
        hrow[ni * 16] = f2bf(s);
      }
    }
  }
}

// ---------------------------------------------------------------------------
// GEMM2: yv[row][d] = sum_f h[row][f] * w2t[e][d][f]    (f32 out)
// Same XCD-pinned swizzle: working set = 2MB B-half + 512KB A-tile.
// ---------------------------------------------------------------------------
__global__ __launch_bounds__(256, 4) void gemm2_kernel(
    const unsigned short* __restrict__ h,    // [2T][F] bf16
    const unsigned short* __restrict__ w2t,  // [E][D][F] bf16
    float* __restrict__ yv,                  // [2T][D] f32
    const int* __restrict__ cnt, const int* __restrict__ off)
{
  // decode swizzled 1-D id: g = (phase*256 + m*4 + nl)*8 + e
  int g = blockIdx.x;
  int e = g & 7;
  int b = g >> 3;              // 0..511
  int phase = b >> 8;          // 0..1
  int m = (b >> 2) & 63;       // 0..63
  int nl = b & 3;              // 0..3
  int count = cnt[e];
  int r0 = m * 128;
  if (r0 >= count) return;
  int n0 = (phase * 4 + nl) * 128;

  __shared__ __align__(16) unsigned short As[8][128][8];   // 16 KB
  __shared__ __align__(16) unsigned short Bs[8][128][8];   // 16 KB

  int tid = threadIdx.x, lane = tid & 63, w = tid >> 6;
  int wr = w >> 1, wc = w & 1;
  int quad = lane >> 4, li = lane & 15;
  size_t yb = (size_t)off[e];

  const unsigned short* ag[2];
  const unsigned short* bg[2];
  for (int c = 0; c < 2; ++c) {
    int mm = c * 64 + lane;
    int r = r0 + mm; if (r > count - 1) r = count - 1;
    ag[c] = h + (yb + r) * FF;
    bg[c] = w2t + ((size_t)e * DIM + (n0 + mm)) * FF;
  }

  floatx4 acc[4][4];
  for (int mi = 0; mi < 4; ++mi)
    for (int ni = 0; ni < 4; ++ni)
      for (int q = 0; q < 4; ++q) acc[mi][ni][q] = 0.0f;

  for (int k0 = 0; k0 < FF; k0 += 64) {
    __syncthreads();
    for (int kk = 0; kk < 2; ++kk) {
      int kq = w + kk * 4;
      gl_lds16(ag[0] + k0 + kq * 8, &As[kq][0][0]);
      gl_lds16(ag[1] + k0 + kq * 8, &As[kq][64][0]);
      gl_lds16(bg[0] + k0 + kq * 8, &Bs[kq][0][0]);
      gl_lds16(bg[1] + k0 + kq * 8, &Bs[kq][64][0]);
    }
    __syncthreads();
    for (int ks = 0; ks < 2; ++ks) {
      bf16x8 af[4], bf[4];
      for (int mi = 0; mi < 4; ++mi)
        af[mi] = *(const bf16x8*)&As[ks * 4 + quad][wr * 64 + mi * 16 + li][0];
      for (int ni = 0; ni < 4; ++ni)
        bf[ni] = *(const bf16x8*)&Bs[ks * 4 + quad][wc * 64 + ni * 16 + li][0];
      for (int mi = 0; mi < 4; ++mi)
        for (int ni = 0; ni < 4; ++ni)
          acc[mi][ni] = __builtin_amdgcn_mfma_f32_16x16x32_bf16(
              af[mi], bf[ni], acc[mi][ni], 0, 0, 0);
    }
  }

  for (int mi = 0; mi < 4; ++mi) {
    int rowb = wr * 64 + mi * 16 + quad * 4;
    for (int rr = 0; rr < 4; ++rr) {
      int r = r0 + rowb + rr;
      if (r >= count) continue;
      float* yrow = yv + (yb + r) * DIM + n0 + wc * 64 + li;
      for (int ni = 0; ni < 4; ++ni)
        yrow[ni * 16] = acc[mi][ni][rr];
    }
  }
}

// ---------------------------------------------------------------------------
// Combine: out[t] = w0 * yv[row0] + w1 * yv[row1]
// ---------------------------------------------------------------------------
__global__ __launch_bounds__(256) void combine_kernel(
    const float* __restrict__ yv, const int* __restrict__ tokEnc,
    const float* __restrict__ tokW, const int* __restrict__ off,
    float* __restrict__ out)
{
  int t = blockIdx.x;
  int i = threadIdx.x;   // 256 threads x float4 = 1024 = D
  int enc0 = tokEnc[2 * t + 0], enc1 = tokEnc[2 * t + 1];
  float w0 = tokW[2 * t + 0], w1 = tokW[2 * t + 1];
  size_t row0 = (size_t)off[enc0 >> 16] + (enc0 & 0xFFFF);
  size_t row1 = (size_t)off[enc1 >> 16] + (enc1 & 0xFFFF);
  float4 a = ((const float4*)(yv + row0 * DIM))[i];
  float4 b = ((const float4*)(yv + row1 * DIM))[i];
  float4 o;
  o.x = w0 * a.x + w1 * b.x;
  o.y = w0 * a.y + w1 * b.y;
  o.z = w0 * a.z + w1 * b.z;
  o.w = w0 * a.w + w1 * b.w;
  ((float4*)(out + (size_t)t * DIM))[i] = o;
}

// ---------------------------------------------------------------------------
extern "C" void kernel_launch(void* const* d_in, const int* in_sizes, int n_in,
                              void* d_out, int out_size, void* d_ws, size_t ws_size,
                              hipStream_t stream)
{
  const float* x  = (const float*)d_in[0];   // [T][D]
  const float* gw = (const float*)d_in[1];   // [D][E]
  const float* w1 = (const float*)d_in[2];   // [E][D][F]
  const float* w2 = (const float*)d_in[3];   // [E][F][D]
  float* out = (float*)d_out;                // [T][D]

  // workspace carve-up (256B aligned)
  size_t o = 0;
  auto alloc = [&](size_t bytes) {
    void* p = (char*)d_ws + o;
    o += (bytes + 255) & ~(size_t)255;
    return p;
  };
  unsigned short* xb   = (unsigned short*)alloc((size_t)T_TOK * DIM * 2);      // 16.8 MB
  unsigned short* w1t  = (unsigned short*)alloc((size_t)NE * DIM * FF * 2);    // 33.6 MB
  unsigned short* w2t  = (unsigned short*)alloc((size_t)NE * DIM * FF * 2);    // 33.6 MB
  unsigned short* hbuf = (unsigned short*)alloc((size_t)T_TOK * TOPK * FF * 2);// 67.1 MB
  float*          yv   = (float*)alloc((size_t)T_TOK * TOPK * DIM * 4);        // 67.1 MB
  int*   tIdx   = (int*)alloc((size_t)NE * T_TOK * 4);
  int*   tokEnc = (int*)alloc((size_t)2 * T_TOK * 4);
  float* tokW   = (float*)alloc((size_t)2 * T_TOK * 4);
  int*   tokExp = (int*)alloc((size_t)T_TOK * 4);
  int*   cnt    = (int*)alloc((size_t)NE * 4);
  int*   off    = (int*)alloc((size_t)(NE + 1) * 4);

  // w1 [E][D][F] -> w1t [E][F][D] ; w2 [E][F][D] -> w2t [E][D][F]
  transpose_bf16_kernel<<<dim3(FF / 32, DIM / 32, NE), 256, 0, stream>>>(w1, w1t, DIM, FF);
  transpose_bf16_kernel<<<dim3(DIM / 32, FF / 32, NE), 256, 0, stream>>>(w2, w2t, FF, DIM);

  gate_kernel<<<T_TOK / 4, 256, 0, stream>>>(x, gw, xb, tokExp, tokW);
  assign_kernel<<<1, 64, 0, stream>>>(tokExp, tokEnc, tIdx, cnt, off);

  // XCD-pinned swizzled 1-D grids (g & 7 = XCD = expert)
  gemm1_kernel<<<8192, 256, 0, stream>>>(xb, w1t, hbuf, tIdx, cnt, off);
  gemm2_kernel<<<4096, 256, 0, stream>>>(hbuf, w2t, yv, cnt, off);
  combine_kernel<<<T_TOK, 256, 0, stream>>>(yv, tokEnc, tokW, off, out);
}